// Round 1
// baseline (1484.349 us; speedup 1.0000x reference)
//
#include <hip/hip_runtime.h>
#include <cstddef>

// Problem constants
#define TT 2048
#define BB 2
#define CC 768
#define NH 12
#define HD 64
#define N3 2304          // 3*NH*HD
#define Y_ELEMS (BB*TT*CC)          // 3145728
#define M_ELEMS (BB*TT*TT)          // 8388608

// ---------------------------------------------------------------------------
// Generic fp32 tiled GEMM:  C[M,N] = A[M,K] @ B[K,N] + bias[N]
// BM=BN=64, BK=16, 256 threads, 4x4 per thread.
// ---------------------------------------------------------------------------
__global__ __launch_bounds__(256) void sgemm_bias(
    const float* __restrict__ A, const float* __restrict__ Bw,
    const float* __restrict__ bias, float* __restrict__ C,
    int M, int N, int K) {
  __shared__ float As[16][64];   // [k][m] (transposed A tile)
  __shared__ float Bs[16][64];   // [k][n]
  int tid = threadIdx.x;
  int tx = tid & 15, ty = tid >> 4;
  int m0 = blockIdx.x * 64, n0 = blockIdx.y * 64;

  int arow = tid >> 2;             // 0..63
  int acol4 = (tid & 3) << 2;      // 0,4,8,12
  int brow = tid >> 4;             // 0..15
  int bcol4 = (tid & 15) << 2;     // 0..60

  const float* Aptr = A + (size_t)(m0 + arow) * K + acol4;
  const float* Bptr = Bw + (size_t)brow * N + n0 + bcol4;

  float acc[4][4] = {};

  for (int k0 = 0; k0 < K; k0 += 16) {
    float4 av = *(const float4*)(Aptr + k0);
    float4 bv = *(const float4*)(Bptr + (size_t)k0 * N);
    As[acol4 + 0][arow] = av.x;
    As[acol4 + 1][arow] = av.y;
    As[acol4 + 2][arow] = av.z;
    As[acol4 + 3][arow] = av.w;
    *(float4*)&Bs[brow][bcol4] = bv;
    __syncthreads();
#pragma unroll
    for (int kk = 0; kk < 16; ++kk) {
      float4 a4 = *(const float4*)&As[kk][ty << 2];
      float4 b4 = *(const float4*)&Bs[kk][tx << 2];
      float a[4] = {a4.x, a4.y, a4.z, a4.w};
      float b[4] = {b4.x, b4.y, b4.z, b4.w};
#pragma unroll
      for (int ii = 0; ii < 4; ++ii)
#pragma unroll
        for (int jj = 0; jj < 4; ++jj) acc[ii][jj] += a[ii] * b[jj];
    }
    __syncthreads();
  }

  float4 bv = *(const float4*)(bias + n0 + (tx << 2));
#pragma unroll
  for (int ii = 0; ii < 4; ++ii) {
    int m = m0 + (ty << 2) + ii;
    float4 o;
    o.x = acc[ii][0] + bv.x;
    o.y = acc[ii][1] + bv.y;
    o.z = acc[ii][2] + bv.z;
    o.w = acc[ii][3] + bv.w;
    *(float4*)(C + (size_t)m * N + n0 + (tx << 2)) = o;
  }
}

// ---------------------------------------------------------------------------
// Head-0 scores: Sbuf[b,i,j] = relu( dot(q0[b,i,:], k0[b,j,:]) / 8 )
// Only lower-triangle tiles (jt <= it) are written; the scan masks the rest.
// ---------------------------------------------------------------------------
__global__ __launch_bounds__(256) void score0_kernel(
    const float* __restrict__ qkv, float* __restrict__ Sbuf) {
  int it = blockIdx.x, jt = blockIdx.y, b = blockIdx.z;
  if (jt > it) return;
  __shared__ float Qs[64][64];  // [d][row]
  __shared__ float Ks[64][64];  // [d][col]
  int tid = threadIdx.x;
  int row = tid >> 2;
  int dq = (tid & 3) << 2;
  int i0 = it * 64, j0 = jt * 64;
  const float* qb = qkv + (size_t)((b * TT) + i0 + row) * N3;        // q head0
  const float* kb = qkv + (size_t)((b * TT) + j0 + row) * N3 + CC;   // k head0
#pragma unroll
  for (int rep = 0; rep < 4; ++rep) {
    int d = dq + rep * 16;
    float4 qv = *(const float4*)(qb + d);
    float4 kv = *(const float4*)(kb + d);
    Qs[d + 0][row] = qv.x; Qs[d + 1][row] = qv.y;
    Qs[d + 2][row] = qv.z; Qs[d + 3][row] = qv.w;
    Ks[d + 0][row] = kv.x; Ks[d + 1][row] = kv.y;
    Ks[d + 2][row] = kv.z; Ks[d + 3][row] = kv.w;
  }
  __syncthreads();
  int tx = tid & 15, ty = tid >> 4;
  float acc[4][4] = {};
#pragma unroll 8
  for (int kk = 0; kk < 64; ++kk) {
    float4 a4 = *(const float4*)&Qs[kk][ty << 2];
    float4 b4 = *(const float4*)&Ks[kk][tx << 2];
    float a[4] = {a4.x, a4.y, a4.z, a4.w};
    float b[4] = {b4.x, b4.y, b4.z, b4.w};
#pragma unroll
    for (int ii = 0; ii < 4; ++ii)
#pragma unroll
      for (int jj = 0; jj < 4; ++jj) acc[ii][jj] += a[ii] * b[jj];
  }
#pragma unroll
  for (int ii = 0; ii < 4; ++ii) {
    int gi = (b * TT) + i0 + (ty << 2) + ii;
    float4 o;
    o.x = fmaxf(acc[ii][0] * 0.125f, 0.f);
    o.y = fmaxf(acc[ii][1] * 0.125f, 0.f);
    o.z = fmaxf(acc[ii][2] * 0.125f, 0.f);
    o.w = fmaxf(acc[ii][3] * 0.125f, 0.f);
    *(float4*)(Sbuf + (size_t)gi * TT + j0 + (tx << 2)) = o;
  }
}

// ---------------------------------------------------------------------------
// Column-wise exclusive prefix scan over rows (chunked, two passes).
// mask = (j>=1 && j<r): implements keep (col0 + diagonal zero) + causal.
// Pass A: per-chunk column sums.  Pass B: in-place S0 -> FF.
// ---------------------------------------------------------------------------
__global__ __launch_bounds__(256) void scan_partial(
    const float* __restrict__ Sbuf, float* __restrict__ partials) {
  int j = blockIdx.x * 256 + threadIdx.x;
  int chunk = blockIdx.y, b = blockIdx.z;
  int r0 = chunk * 128;
  const float* base = Sbuf + (size_t)(b * TT + r0) * TT + j;
  float sum = 0.f;
  for (int rr = 0; rr < 128; ++rr) {
    int r = r0 + rr;
    float v = (j >= 1 && j < r) ? base[(size_t)rr * TT] : 0.f;
    sum += v;
  }
  partials[(size_t)(b * 16 + chunk) * TT + j] = sum;
}

__global__ __launch_bounds__(256) void scan_write(
    float* __restrict__ Sbuf, const float* __restrict__ partials) {
  int j = blockIdx.x * 256 + threadIdx.x;
  int chunk = blockIdx.y, b = blockIdx.z;
  float run = 0.f;
  for (int c = 0; c < chunk; ++c) run += partials[(size_t)(b * 16 + c) * TT + j];
  int r0 = chunk * 128;
  float* base = Sbuf + (size_t)(b * TT + r0) * TT + j;
  for (int rr = 0; rr < 128; ++rr) {
    int r = r0 + rr;
    float v = (j >= 1 && j < r) ? base[(size_t)rr * TT] : 0.f;
    base[(size_t)rr * TT] = run;   // FF[b,r,j] = sum_{r'<r} S[r',j]
    run += v;
  }
}

// ---------------------------------------------------------------------------
// FF_sum[b,i] = sum_j clip(FF[b,i,j], 0, 1)
// ---------------------------------------------------------------------------
__global__ __launch_bounds__(256) void ffsum_kernel(
    const float* __restrict__ FF, float* __restrict__ ffsum) {
  int i = blockIdx.x, b = blockIdx.y;
  const float4* row = (const float4*)(FF + (size_t)(b * TT + i) * TT);
  float s = 0.f;
  for (int r = threadIdx.x; r < TT / 4; r += 256) {
    float4 v = row[r];
    s += fminf(fmaxf(v.x, 0.f), 1.f) + fminf(fmaxf(v.y, 0.f), 1.f) +
         fminf(fmaxf(v.z, 0.f), 1.f) + fminf(fmaxf(v.w, 0.f), 1.f);
  }
#pragma unroll
  for (int o = 1; o < 64; o <<= 1) s += __shfl_xor(s, o);
  __shared__ float ws[4];
  if ((threadIdx.x & 63) == 0) ws[threadIdx.x >> 6] = s;
  __syncthreads();
  if (threadIdx.x == 0) ffsum[b * TT + i] = ws[0] + ws[1] + ws[2] + ws[3];
}

// ---------------------------------------------------------------------------
// Flash-style causal attention with -FF shift, fp32.
// Block = (qtile, head, batch); 64 query rows; 4 threads per row (g=0..3).
// ---------------------------------------------------------------------------
__global__ __launch_bounds__(256) void attn_kernel(
    const float* __restrict__ qkv, const float* __restrict__ FF,
    float* __restrict__ yh) {
  __shared__ float Qs[64][68], Ks[64][68], Vs[64][68], Ps[64][68];
  int qt = blockIdx.x, h = blockIdx.y, b = blockIdx.z;
  int tid = threadIdx.x;
  int i = tid >> 2, g = tid & 3;
  int i0 = qt * 64;
  int ig = i0 + i;

  {  // stage Q tile
    int row = tid >> 2, dq = (tid & 3) << 2;
    const float* qb = qkv + (size_t)((b * TT) + i0 + row) * N3 + h * HD;
#pragma unroll
    for (int rep = 0; rep < 4; ++rep) {
      int d = dq + rep * 16;
      *(float4*)&Qs[row][d] = *(const float4*)(qb + d);
    }
  }
  __syncthreads();
  float4 qreg[16];
#pragma unroll
  for (int d4 = 0; d4 < 16; ++d4) qreg[d4] = *(const float4*)&Qs[i][d4 * 4];

  float4 acc[4];
#pragma unroll
  for (int d4 = 0; d4 < 4; ++d4) acc[d4] = make_float4(0.f, 0.f, 0.f, 0.f);
  float mrun = -INFINITY, lrun = 0.f;
  const float* ffrow = FF + (size_t)(b * TT + ig) * TT;

  for (int kt = 0; kt <= qt; ++kt) {
    int j0 = kt * 64;
    __syncthreads();  // previous PV done reading Ks/Vs/Ps
    {                 // stage K,V tiles
      int row = tid >> 2, dq = (tid & 3) << 2;
      const float* kb = qkv + (size_t)((b * TT) + j0 + row) * N3 + CC + h * HD;
      const float* vb = kb + CC;
#pragma unroll
      for (int rep = 0; rep < 4; ++rep) {
        int d = dq + rep * 16;
        *(float4*)&Ks[row][d] = *(const float4*)(kb + d);
        *(float4*)&Vs[row][d] = *(const float4*)(vb + d);
      }
    }
    __syncthreads();

    // scores for 16 columns j = g*16 + jj
    float p[16];
    float mloc = -INFINITY;
#pragma unroll
    for (int jj = 0; jj < 16; ++jj) {
      int j = g * 16 + jj;
      int jg = j0 + j;
      float sacc = 0.f;
#pragma unroll
      for (int d4 = 0; d4 < 16; ++d4) {
        float4 kv = *(const float4*)&Ks[j][d4 * 4];
        sacc += qreg[d4].x * kv.x + qreg[d4].y * kv.y +
                qreg[d4].z * kv.z + qreg[d4].w * kv.w;
      }
      float sv = (jg <= ig) ? (sacc * 0.125f - ffrow[jg]) : -INFINITY;
      p[jj] = sv;
      mloc = fmaxf(mloc, sv);
    }
    mloc = fmaxf(mloc, __shfl_xor(mloc, 1));
    mloc = fmaxf(mloc, __shfl_xor(mloc, 2));
    float mnew = fmaxf(mrun, mloc);
    float scale = __expf(mrun - mnew);  // exp(-inf - finite) = 0 first tile
    lrun *= scale;
#pragma unroll
    for (int d4 = 0; d4 < 4; ++d4) {
      acc[d4].x *= scale; acc[d4].y *= scale;
      acc[d4].z *= scale; acc[d4].w *= scale;
    }
    float psum = 0.f;
#pragma unroll
    for (int jj = 0; jj < 16; ++jj) {
      float pv = __expf(p[jj] - mnew);
      Ps[i][g * 16 + jj] = pv;
      psum += pv;
    }
    psum += __shfl_xor(psum, 1);
    psum += __shfl_xor(psum, 2);
    lrun += psum;
    mrun = mnew;
    __syncthreads();  // Ps visible

    // PV: acc[d] += sum_j P[i][j] * V[j][d], this thread owns d = g*16..g*16+15
#pragma unroll 8
    for (int j = 0; j < 64; ++j) {
      float pj = Ps[i][j];
      float4 v0 = *(const float4*)&Vs[j][g * 16 + 0];
      float4 v1 = *(const float4*)&Vs[j][g * 16 + 4];
      float4 v2 = *(const float4*)&Vs[j][g * 16 + 8];
      float4 v3 = *(const float4*)&Vs[j][g * 16 + 12];
      acc[0].x += pj * v0.x; acc[0].y += pj * v0.y; acc[0].z += pj * v0.z; acc[0].w += pj * v0.w;
      acc[1].x += pj * v1.x; acc[1].y += pj * v1.y; acc[1].z += pj * v1.z; acc[1].w += pj * v1.w;
      acc[2].x += pj * v2.x; acc[2].y += pj * v2.y; acc[2].z += pj * v2.z; acc[2].w += pj * v2.w;
      acc[3].x += pj * v3.x; acc[3].y += pj * v3.y; acc[3].z += pj * v3.z; acc[3].w += pj * v3.w;
    }
  }

  float inv = 1.f / lrun;
  float* outb = yh + (size_t)(b * TT + ig) * CC + h * HD + g * 16;
#pragma unroll
  for (int d4 = 0; d4 < 4; ++d4) {
    float4 o;
    o.x = acc[d4].x * inv; o.y = acc[d4].y * inv;
    o.z = acc[d4].z * inv; o.w = acc[d4].w * inv;
    *(float4*)(outb + d4 * 4) = o;
  }
}

// ---------------------------------------------------------------------------
// M[0,b,i,j] = i - ffsum[b,j]   (overwrites the FF buffer region of d_out)
// ---------------------------------------------------------------------------
__global__ __launch_bounds__(256) void m_kernel(
    const float* __restrict__ ffsum, float* __restrict__ Mout) {
  int idx = blockIdx.x * blockDim.x + threadIdx.x;
  int stride = gridDim.x * blockDim.x;
  for (; idx < M_ELEMS; idx += stride) {
    int j = idx & (TT - 1);
    int i = (idx >> 11) & (TT - 1);
    int b = idx >> 22;
    Mout[idx] = (float)i - ffsum[(b << 11) + j];
  }
}

// ---------------------------------------------------------------------------
extern "C" void kernel_launch(void* const* d_in, const int* in_sizes, int n_in,
                              void* d_out, int out_size, void* d_ws, size_t ws_size,
                              hipStream_t stream) {
  const float* x      = (const float*)d_in[0];
  const float* w_attn = (const float*)d_in[1];
  const float* b_attn = (const float*)d_in[2];
  const float* w_proj = (const float*)d_in[3];
  const float* b_proj = (const float*)d_in[4];

  float* y    = (float*)d_out;          // [B,T,C]
  float* Mreg = y + Y_ELEMS;            // [B,T,T]: S0 -> FF (scratch) -> M (final)

  float* ws       = (float*)d_ws;
  float* qkv      = ws;                     // B*T*2304 = 9437184
  float* partials = qkv + (size_t)BB * TT * N3;   // B*16*T  = 65536
  float* ffsum    = partials + BB * 16 * TT;      // B*T     = 4096
  float* yh       = ffsum + BB * TT;              // B*T*C   = 3145728
  // total ws usage: ~50.6 MB

  // 1. QKV = x @ w_attn + b_attn
  sgemm_bias<<<dim3(64, 36), 256, 0, stream>>>(x, w_attn, b_attn, qkv, BB * TT, N3, CC);
  // 2. head-0 scores (relu'd) into Mreg (lower-triangle tiles)
  score0_kernel<<<dim3(32, 32, BB), 256, 0, stream>>>(qkv, Mreg);
  // 3. column-wise exclusive scan (in place): Mreg = FF
  scan_partial<<<dim3(8, 16, BB), 256, 0, stream>>>(Mreg, partials);
  scan_write<<<dim3(8, 16, BB), 256, 0, stream>>>(Mreg, partials);
  // 4. FF_sum
  ffsum_kernel<<<dim3(TT, BB), 256, 0, stream>>>(Mreg, ffsum);
  // 5. attention (reads FF from Mreg)
  attn_kernel<<<dim3(32, NH, BB), 256, 0, stream>>>(qkv, Mreg, yh);
  // 6. M output (overwrites Mreg AFTER attention consumed FF)
  m_kernel<<<4096, 256, 0, stream>>>(ffsum, Mreg);
  // 7. y = yh @ w_proj + b_proj
  sgemm_bias<<<dim3(64, 12), 256, 0, stream>>>(yh, w_proj, b_proj, y, BB * TT, CC, CC);
}

// Round 2
// 678.106 us; speedup vs baseline: 2.1890x; 2.1890x over previous
//
#include <hip/hip_runtime.h>
#include <cstddef>

// Problem constants
#define TT 2048
#define BB 2
#define CC 768
#define NH 12
#define HD 64
#define N3 2304          // 3*NH*HD
#define Y_ELEMS (BB*TT*CC)          // 3145728
#define M_ELEMS (BB*TT*TT)          // 8388608

typedef __attribute__((ext_vector_type(8))) short bf16x8;
typedef __attribute__((ext_vector_type(4))) float f32x4;

__device__ inline unsigned short f2b(float f) {
  union { float f; unsigned u; } v; v.f = f;
  unsigned r = (v.u + 0x7FFFu + ((v.u >> 16) & 1u)) >> 16;
  return (unsigned short)r;
}

// ---------------------------------------------------------------------------
// Generic fp32 tiled GEMM:  C[M,N] = A[M,K] @ B[K,N] + bias[N]
// ---------------------------------------------------------------------------
__global__ __launch_bounds__(256) void sgemm_bias(
    const float* __restrict__ A, const float* __restrict__ Bw,
    const float* __restrict__ bias, float* __restrict__ C,
    int M, int N, int K) {
  __shared__ float As[16][64];   // [k][m]
  __shared__ float Bs[16][64];   // [k][n]
  int tid = threadIdx.x;
  int tx = tid & 15, ty = tid >> 4;
  int m0 = blockIdx.x * 64, n0 = blockIdx.y * 64;

  int arow = tid >> 2;
  int acol4 = (tid & 3) << 2;
  int brow = tid >> 4;
  int bcol4 = (tid & 15) << 2;

  const float* Aptr = A + (size_t)(m0 + arow) * K + acol4;
  const float* Bptr = Bw + (size_t)brow * N + n0 + bcol4;

  float acc[4][4] = {};

  for (int k0 = 0; k0 < K; k0 += 16) {
    float4 av = *(const float4*)(Aptr + k0);
    float4 bv = *(const float4*)(Bptr + (size_t)k0 * N);
    As[acol4 + 0][arow] = av.x;
    As[acol4 + 1][arow] = av.y;
    As[acol4 + 2][arow] = av.z;
    As[acol4 + 3][arow] = av.w;
    *(float4*)&Bs[brow][bcol4] = bv;
    __syncthreads();
#pragma unroll
    for (int kk = 0; kk < 16; ++kk) {
      float4 a4 = *(const float4*)&As[kk][ty << 2];
      float4 b4 = *(const float4*)&Bs[kk][tx << 2];
      float a[4] = {a4.x, a4.y, a4.z, a4.w};
      float b[4] = {b4.x, b4.y, b4.z, b4.w};
#pragma unroll
      for (int ii = 0; ii < 4; ++ii)
#pragma unroll
        for (int jj = 0; jj < 4; ++jj) acc[ii][jj] += a[ii] * b[jj];
    }
    __syncthreads();
  }

  float4 bv = *(const float4*)(bias + n0 + (tx << 2));
#pragma unroll
  for (int ii = 0; ii < 4; ++ii) {
    int m = m0 + (ty << 2) + ii;
    float4 o;
    o.x = acc[ii][0] + bv.x;
    o.y = acc[ii][1] + bv.y;
    o.z = acc[ii][2] + bv.z;
    o.w = acc[ii][3] + bv.w;
    *(float4*)(C + (size_t)m * N + n0 + (tx << 2)) = o;
  }
}

// ---------------------------------------------------------------------------
// Head-0 scores (fp32, precision-critical for the FF cumsum):
// Sbuf[b,i,j] = relu( dot(q0[b,i,:], k0[b,j,:]) / 8 ), lower-triangle tiles.
// ---------------------------------------------------------------------------
__global__ __launch_bounds__(256) void score0_kernel(
    const float* __restrict__ qkv, float* __restrict__ Sbuf) {
  int it = blockIdx.x, jt = blockIdx.y, b = blockIdx.z;
  if (jt > it) return;
  __shared__ float Qs[64][64];
  __shared__ float Ks[64][64];
  int tid = threadIdx.x;
  int row = tid >> 2;
  int dq = (tid & 3) << 2;
  int i0 = it * 64, j0 = jt * 64;
  const float* qb = qkv + (size_t)((b * TT) + i0 + row) * N3;
  const float* kb = qkv + (size_t)((b * TT) + j0 + row) * N3 + CC;
#pragma unroll
  for (int rep = 0; rep < 4; ++rep) {
    int d = dq + rep * 16;
    float4 qv = *(const float4*)(qb + d);
    float4 kv = *(const float4*)(kb + d);
    Qs[d + 0][row] = qv.x; Qs[d + 1][row] = qv.y;
    Qs[d + 2][row] = qv.z; Qs[d + 3][row] = qv.w;
    Ks[d + 0][row] = kv.x; Ks[d + 1][row] = kv.y;
    Ks[d + 2][row] = kv.z; Ks[d + 3][row] = kv.w;
  }
  __syncthreads();
  int tx = tid & 15, ty = tid >> 4;
  float acc[4][4] = {};
#pragma unroll 8
  for (int kk = 0; kk < 64; ++kk) {
    float4 a4 = *(const float4*)&Qs[kk][ty << 2];
    float4 b4 = *(const float4*)&Ks[kk][tx << 2];
    float a[4] = {a4.x, a4.y, a4.z, a4.w};
    float b[4] = {b4.x, b4.y, b4.z, b4.w};
#pragma unroll
    for (int ii = 0; ii < 4; ++ii)
#pragma unroll
      for (int jj = 0; jj < 4; ++jj) acc[ii][jj] += a[ii] * b[jj];
  }
#pragma unroll
  for (int ii = 0; ii < 4; ++ii) {
    int gi = (b * TT) + i0 + (ty << 2) + ii;
    float4 o;
    o.x = fmaxf(acc[ii][0] * 0.125f, 0.f);
    o.y = fmaxf(acc[ii][1] * 0.125f, 0.f);
    o.z = fmaxf(acc[ii][2] * 0.125f, 0.f);
    o.w = fmaxf(acc[ii][3] * 0.125f, 0.f);
    *(float4*)(Sbuf + (size_t)gi * TT + j0 + (tx << 2)) = o;
  }
}

// ---------------------------------------------------------------------------
// Column-wise exclusive prefix scan over rows (chunked, two passes).
// ---------------------------------------------------------------------------
__global__ __launch_bounds__(256) void scan_partial(
    const float* __restrict__ Sbuf, float* __restrict__ partials) {
  int j = blockIdx.x * 256 + threadIdx.x;
  int chunk = blockIdx.y, b = blockIdx.z;
  int r0 = chunk * 128;
  const float* base = Sbuf + (size_t)(b * TT + r0) * TT + j;
  float sum = 0.f;
  for (int rr = 0; rr < 128; ++rr) {
    int r = r0 + rr;
    float v = (j >= 1 && j < r) ? base[(size_t)rr * TT] : 0.f;
    sum += v;
  }
  partials[(size_t)(b * 16 + chunk) * TT + j] = sum;
}

__global__ __launch_bounds__(256) void scan_write(
    float* __restrict__ Sbuf, const float* __restrict__ partials) {
  int j = blockIdx.x * 256 + threadIdx.x;
  int chunk = blockIdx.y, b = blockIdx.z;
  float run = 0.f;
  for (int c = 0; c < chunk; ++c) run += partials[(size_t)(b * 16 + c) * TT + j];
  int r0 = chunk * 128;
  float* base = Sbuf + (size_t)(b * TT + r0) * TT + j;
  for (int rr = 0; rr < 128; ++rr) {
    int r = r0 + rr;
    float v = (j >= 1 && j < r) ? base[(size_t)rr * TT] : 0.f;
    base[(size_t)rr * TT] = run;
    run += v;
  }
}

// ---------------------------------------------------------------------------
// FF_sum[b,i] = sum_j clip(FF[b,i,j], 0, 1)
// ---------------------------------------------------------------------------
__global__ __launch_bounds__(256) void ffsum_kernel(
    const float* __restrict__ FF, float* __restrict__ ffsum) {
  int i = blockIdx.x, b = blockIdx.y;
  const float4* row = (const float4*)(FF + (size_t)(b * TT + i) * TT);
  float s = 0.f;
  for (int r = threadIdx.x; r < TT / 4; r += 256) {
    float4 v = row[r];
    s += fminf(fmaxf(v.x, 0.f), 1.f) + fminf(fmaxf(v.y, 0.f), 1.f) +
         fminf(fmaxf(v.z, 0.f), 1.f) + fminf(fmaxf(v.w, 0.f), 1.f);
  }
#pragma unroll
  for (int o = 1; o < 64; o <<= 1) s += __shfl_xor(s, o);
  __shared__ float ws[4];
  if ((threadIdx.x & 63) == 0) ws[threadIdx.x >> 6] = s;
  __syncthreads();
  if (threadIdx.x == 0) ffsum[b * TT + i] = ws[0] + ws[1] + ws[2] + ws[3];
}

// ---------------------------------------------------------------------------
// Pack qkv fp32 -> head-major bf16 Q,K and transposed V (Vt[bh][d][t]).
// Block = (h, ttile64, b).
// ---------------------------------------------------------------------------
__global__ __launch_bounds__(256) void prep_qkv(
    const float* __restrict__ qkv, unsigned short* __restrict__ Qb,
    unsigned short* __restrict__ Kb, unsigned short* __restrict__ Vt) {
  int h = blockIdx.x, tt = blockIdx.y, b = blockIdx.z;
  int t0 = tt * 64;
  int bh = b * NH + h;
  __shared__ float vt[64][65];
  const float* base = qkv + (size_t)(b * TT + t0) * N3 + h * HD;
#pragma unroll
  for (int rep = 0; rep < 4; ++rep) {
    int idx = threadIdx.x + rep * 256;
    int r = idx >> 4, c = (idx & 15) << 2;
    float4 qv = *(const float4*)(base + (size_t)r * N3 + c);
    float4 kv = *(const float4*)(base + (size_t)r * N3 + CC + c);
    float4 vv = *(const float4*)(base + (size_t)r * N3 + 2 * CC + c);
    ushort4 qo; qo.x = f2b(qv.x); qo.y = f2b(qv.y); qo.z = f2b(qv.z); qo.w = f2b(qv.w);
    ushort4 ko; ko.x = f2b(kv.x); ko.y = f2b(kv.y); ko.z = f2b(kv.z); ko.w = f2b(kv.w);
    *(ushort4*)(Qb + ((size_t)bh * TT + t0 + r) * HD + c) = qo;
    *(ushort4*)(Kb + ((size_t)bh * TT + t0 + r) * HD + c) = ko;
    vt[c + 0][r] = vv.x; vt[c + 1][r] = vv.y;
    vt[c + 2][r] = vv.z; vt[c + 3][r] = vv.w;
  }
  __syncthreads();
#pragma unroll
  for (int rep = 0; rep < 4; ++rep) {
    int idx = threadIdx.x + rep * 256;
    int d = idx >> 4, t4 = (idx & 15) << 2;
    ushort4 vo;
    vo.x = f2b(vt[d][t4 + 0]); vo.y = f2b(vt[d][t4 + 1]);
    vo.z = f2b(vt[d][t4 + 2]); vo.w = f2b(vt[d][t4 + 3]);
    *(ushort4*)(Vt + ((size_t)bh * HD + d) * TT + t0 + t4) = vo;
  }
}

// ---------------------------------------------------------------------------
// bf16 MFMA flash attention with fp32 -FF shift.
// Block = 4 independent waves; wave handles 32 q-rows of one (b,h).
// Fragments read directly from global (K/V are L2-resident per head).
// P re-layout via per-wave LDS tile. No __syncthreads anywhere.
// ---------------------------------------------------------------------------
__global__ __launch_bounds__(256) void attn_mfma(
    const unsigned short* __restrict__ Qb, const unsigned short* __restrict__ Kb,
    const unsigned short* __restrict__ Vt, const float* __restrict__ FF,
    float* __restrict__ yh) {
  int h = blockIdx.x, qt = 15 - blockIdx.y, b = blockIdx.z;
  int wave = threadIdx.x >> 6, lane = threadIdx.x & 63;
  int lr = lane & 15, lg = lane >> 4;
  int i0 = qt * 128 + wave * 32;
  int bh = b * NH + h;
  const unsigned short* Qh = Qb + (size_t)bh * TT * HD;
  const unsigned short* Kh = Kb + (size_t)bh * TT * HD;
  const unsigned short* Vh = Vt + (size_t)bh * HD * TT;

  __shared__ __align__(16) unsigned short Plds[4][32][72];

  // Q fragments: lane holds Q[i0 + mi*16 + lr][ks*32 + lg*8 .. +7]
  bf16x8 qf[2][2];
#pragma unroll
  for (int mi = 0; mi < 2; ++mi)
#pragma unroll
    for (int ks = 0; ks < 2; ++ks)
      qf[mi][ks] = *(const bf16x8*)(Qh + (size_t)(i0 + mi * 16 + lr) * HD + ks * 32 + lg * 8);

  f32x4 acc[2][4];
  float mrun[2][4], lrun[2][4];
#pragma unroll
  for (int mi = 0; mi < 2; ++mi)
#pragma unroll
    for (int q = 0; q < 4; ++q) {
      acc[mi][q] = (f32x4){0.f, 0.f, 0.f, 0.f};
      mrun[mi][q] = -1e30f;
      lrun[mi][q] = 0.f;
    }

  int ktend = (i0 + 31) >> 6;
  for (int kt = 0; kt <= ktend; ++kt) {
    int j0 = kt * 64;
    // ---- QK^T: S[i][j], D layout row=lg*4+r, col=lr ----
    f32x4 s[2][4];
#pragma unroll
    for (int nj = 0; nj < 4; ++nj) {
      bf16x8 kf0 = *(const bf16x8*)(Kh + (size_t)(j0 + nj * 16 + lr) * HD + lg * 8);
      bf16x8 kf1 = *(const bf16x8*)(Kh + (size_t)(j0 + nj * 16 + lr) * HD + 32 + lg * 8);
#pragma unroll
      for (int mi = 0; mi < 2; ++mi) {
        f32x4 z = (f32x4){0.f, 0.f, 0.f, 0.f};
        z = __builtin_amdgcn_mfma_f32_16x16x32_bf16(qf[mi][0], kf0, z, 0, 0, 0);
        s[mi][nj] = __builtin_amdgcn_mfma_f32_16x16x32_bf16(qf[mi][1], kf1, z, 0, 0, 0);
      }
    }
    // ---- logits (-FF in fp32), online softmax ----
#pragma unroll
    for (int mi = 0; mi < 2; ++mi) {
      int ibase = i0 + mi * 16 + lg * 4;
      const float* ffb = FF + ((size_t)(b * TT) + ibase) * TT + j0 + lr;
      float mt[4] = {-1e30f, -1e30f, -1e30f, -1e30f};
#pragma unroll
      for (int nj = 0; nj < 4; ++nj) {
#pragma unroll
        for (int r = 0; r < 4; ++r) {
          int ig = ibase + r, jg = j0 + nj * 16 + lr;
          float ff = ffb[(size_t)r * TT + nj * 16];
          float lv = (jg <= ig) ? s[mi][nj][r] * 0.125f - ff : -1e30f;
          s[mi][nj][r] = lv;
          mt[r] = fmaxf(mt[r], lv);
        }
      }
#pragma unroll
      for (int r = 0; r < 4; ++r) {
        mt[r] = fmaxf(mt[r], __shfl_xor(mt[r], 1));
        mt[r] = fmaxf(mt[r], __shfl_xor(mt[r], 2));
        mt[r] = fmaxf(mt[r], __shfl_xor(mt[r], 4));
        mt[r] = fmaxf(mt[r], __shfl_xor(mt[r], 8));
        float mnew = fmaxf(mrun[mi][r], mt[r]);
        float scl = __expf(mrun[mi][r] - mnew);
        mrun[mi][r] = mnew;
        lrun[mi][r] *= scl;
#pragma unroll
        for (int nd = 0; nd < 4; ++nd) acc[mi][nd][r] *= scl;
      }
      float ps[4] = {0.f, 0.f, 0.f, 0.f};
#pragma unroll
      for (int nj = 0; nj < 4; ++nj)
#pragma unroll
        for (int r = 0; r < 4; ++r) {
          float p = __expf(s[mi][nj][r] - mrun[mi][r]);
          ps[r] += p;
          Plds[wave][mi * 16 + lg * 4 + r][nj * 16 + lr] = f2b(p);
        }
#pragma unroll
      for (int r = 0; r < 4; ++r) {
        ps[r] += __shfl_xor(ps[r], 1);
        ps[r] += __shfl_xor(ps[r], 2);
        ps[r] += __shfl_xor(ps[r], 4);
        ps[r] += __shfl_xor(ps[r], 8);
        lrun[mi][r] += ps[r];
      }
    }
    // ---- PV: O[i][d] += P[i][j] V[j][d] ----
#pragma unroll
    for (int ks = 0; ks < 2; ++ks) {
      bf16x8 pa[2];
#pragma unroll
      for (int mi = 0; mi < 2; ++mi)
        pa[mi] = *(const bf16x8*)&Plds[wave][mi * 16 + lr][ks * 32 + lg * 8];
#pragma unroll
      for (int nd = 0; nd < 4; ++nd) {
        bf16x8 vf = *(const bf16x8*)(Vh + (size_t)(nd * 16 + lr) * TT + j0 + ks * 32 + lg * 8);
#pragma unroll
        for (int mi = 0; mi < 2; ++mi)
          acc[mi][nd] = __builtin_amdgcn_mfma_f32_16x16x32_bf16(pa[mi], vf, acc[mi][nd], 0, 0, 0);
      }
    }
  }
  // ---- epilogue ----
#pragma unroll
  for (int mi = 0; mi < 2; ++mi)
#pragma unroll
    for (int r = 0; r < 4; ++r) {
      float inv = 1.f / lrun[mi][r];
      int ig = i0 + mi * 16 + lg * 4 + r;
      float* ob = yh + (size_t)(b * TT + ig) * CC + h * HD;
#pragma unroll
      for (int nd = 0; nd < 4; ++nd)
        ob[nd * 16 + lr] = acc[mi][nd][r] * inv;
    }
}

// ---------------------------------------------------------------------------
// M[0,b,i,j] = i - ffsum[b,j]
// ---------------------------------------------------------------------------
__global__ __launch_bounds__(256) void m_kernel(
    const float* __restrict__ ffsum, float* __restrict__ Mout) {
  int idx = blockIdx.x * blockDim.x + threadIdx.x;
  int stride = gridDim.x * blockDim.x;
  for (; idx < M_ELEMS; idx += stride) {
    int j = idx & (TT - 1);
    int i = (idx >> 11) & (TT - 1);
    int b = idx >> 22;
    Mout[idx] = (float)i - ffsum[(b << 11) + j];
  }
}

// ---------------------------------------------------------------------------
extern "C" void kernel_launch(void* const* d_in, const int* in_sizes, int n_in,
                              void* d_out, int out_size, void* d_ws, size_t ws_size,
                              hipStream_t stream) {
  const float* x      = (const float*)d_in[0];
  const float* w_attn = (const float*)d_in[1];
  const float* b_attn = (const float*)d_in[2];
  const float* w_proj = (const float*)d_in[3];
  const float* b_proj = (const float*)d_in[4];

  float* y    = (float*)d_out;          // [B,T,C]
  float* Mreg = y + Y_ELEMS;            // [B,T,T]: S0 -> FF (scratch) -> M (final)

  float* ws = (float*)d_ws;
  float* qkv = ws;                                 // 9,437,184 f32 (37.7 MB)
  float* yh  = ws;                                 // aliases qkv (qkv dead before attn writes yh)
  float* partials = qkv + (size_t)BB * TT * N3;    // B*16*T
  float* ffsum    = partials + BB * 16 * TT;       // B*T
  unsigned short* Qb = (unsigned short*)(ffsum + BB * TT);
  unsigned short* Kb = Qb + (size_t)BB * NH * TT * HD;   // 3,145,728 each
  unsigned short* Vt = Kb + (size_t)BB * NH * TT * HD;
  // total ws usage ~= 57 MB

  // 1. QKV = x @ w_attn + b_attn  (fp32 — head-0 q,k feed the FF cumsum)
  sgemm_bias<<<dim3(64, 36), 256, 0, stream>>>(x, w_attn, b_attn, qkv, BB * TT, N3, CC);
  // 2. head-0 scores (relu'd, fp32) into Mreg
  score0_kernel<<<dim3(32, 32, BB), 256, 0, stream>>>(qkv, Mreg);
  // 3. column-wise exclusive scan (in place): Mreg = FF
  scan_partial<<<dim3(8, 16, BB), 256, 0, stream>>>(Mreg, partials);
  scan_write<<<dim3(8, 16, BB), 256, 0, stream>>>(Mreg, partials);
  // 4. FF_sum
  ffsum_kernel<<<dim3(TT, BB), 256, 0, stream>>>(Mreg, ffsum);
  // 5. pack to bf16 head-major Q,K + transposed V (last reader of qkv)
  prep_qkv<<<dim3(NH, 32, BB), 256, 0, stream>>>(qkv, Qb, Kb, Vt);
  // 6. MFMA flash attention (reads FF from Mreg; writes yh over dead qkv)
  attn_mfma<<<dim3(NH, 16, BB), 256, 0, stream>>>(Qb, Kb, Vt, Mreg, yh);
  // 7. M output (overwrites Mreg AFTER attention consumed FF)
  m_kernel<<<4096, 256, 0, stream>>>(ffsum, Mreg);
  // 8. y = yh @ w_proj + b_proj
  sgemm_bias<<<dim3(64, 12), 256, 0, stream>>>(yh, w_proj, b_proj, y, BB * TT, CC, CC);
}

// Round 3
// 520.025 us; speedup vs baseline: 2.8544x; 1.3040x over previous
//
#include <hip/hip_runtime.h>
#include <cstddef>

// Problem constants
#define TT 2048
#define BB 2
#define CC 768
#define NH 12
#define HD 64
#define N3 2304          // 3*NH*HD
#define Y_ELEMS (BB*TT*CC)          // 3145728
#define M_ELEMS (BB*TT*TT)          // 8388608

typedef __attribute__((ext_vector_type(8))) short bf16x8;
typedef __attribute__((ext_vector_type(4))) float f32x4;

__device__ inline unsigned short f2b(float f) {
  union { float f; unsigned u; } v; v.f = f;
  unsigned r = (v.u + 0x7FFFu + ((v.u >> 16) & 1u)) >> 16;
  return (unsigned short)r;
}

// ---------------------------------------------------------------------------
// Generic fp32 tiled GEMM:  C[M,N] = A[M,K] @ B[K,N] + bias[N]
// ---------------------------------------------------------------------------
__global__ __launch_bounds__(256) void sgemm_bias(
    const float* __restrict__ A, const float* __restrict__ Bw,
    const float* __restrict__ bias, float* __restrict__ C,
    int M, int N, int K) {
  __shared__ float As[16][64];   // [k][m]
  __shared__ float Bs[16][64];   // [k][n]
  int tid = threadIdx.x;
  int tx = tid & 15, ty = tid >> 4;
  int m0 = blockIdx.x * 64, n0 = blockIdx.y * 64;

  int arow = tid >> 2;
  int acol4 = (tid & 3) << 2;
  int brow = tid >> 4;
  int bcol4 = (tid & 15) << 2;

  const float* Aptr = A + (size_t)(m0 + arow) * K + acol4;
  const float* Bptr = Bw + (size_t)brow * N + n0 + bcol4;

  float acc[4][4] = {};

  for (int k0 = 0; k0 < K; k0 += 16) {
    float4 av = *(const float4*)(Aptr + k0);
    float4 bv = *(const float4*)(Bptr + (size_t)k0 * N);
    As[acol4 + 0][arow] = av.x;
    As[acol4 + 1][arow] = av.y;
    As[acol4 + 2][arow] = av.z;
    As[acol4 + 3][arow] = av.w;
    *(float4*)&Bs[brow][bcol4] = bv;
    __syncthreads();
#pragma unroll
    for (int kk = 0; kk < 16; ++kk) {
      float4 a4 = *(const float4*)&As[kk][ty << 2];
      float4 b4 = *(const float4*)&Bs[kk][tx << 2];
      float a[4] = {a4.x, a4.y, a4.z, a4.w};
      float b[4] = {b4.x, b4.y, b4.z, b4.w};
#pragma unroll
      for (int ii = 0; ii < 4; ++ii)
#pragma unroll
        for (int jj = 0; jj < 4; ++jj) acc[ii][jj] += a[ii] * b[jj];
    }
    __syncthreads();
  }

  float4 bv = *(const float4*)(bias + n0 + (tx << 2));
#pragma unroll
  for (int ii = 0; ii < 4; ++ii) {
    int m = m0 + (ty << 2) + ii;
    float4 o;
    o.x = acc[ii][0] + bv.x;
    o.y = acc[ii][1] + bv.y;
    o.z = acc[ii][2] + bv.z;
    o.w = acc[ii][3] + bv.w;
    *(float4*)(C + (size_t)m * N + n0 + (tx << 2)) = o;
  }
}

// ---------------------------------------------------------------------------
// Head-0 scores (fp32, precision-critical for the FF cumsum):
// Sbuf[b,i,j] = relu( dot(q0[b,i,:], k0[b,j,:]) / 8 ), lower-triangle tiles.
// ---------------------------------------------------------------------------
__global__ __launch_bounds__(256) void score0_kernel(
    const float* __restrict__ qkv, float* __restrict__ Sbuf) {
  int it = blockIdx.x, jt = blockIdx.y, b = blockIdx.z;
  if (jt > it) return;
  __shared__ float Qs[64][64];
  __shared__ float Ks[64][64];
  int tid = threadIdx.x;
  int row = tid >> 2;
  int dq = (tid & 3) << 2;
  int i0 = it * 64, j0 = jt * 64;
  const float* qb = qkv + (size_t)((b * TT) + i0 + row) * N3;
  const float* kb = qkv + (size_t)((b * TT) + j0 + row) * N3 + CC;
#pragma unroll
  for (int rep = 0; rep < 4; ++rep) {
    int d = dq + rep * 16;
    float4 qv = *(const float4*)(qb + d);
    float4 kv = *(const float4*)(kb + d);
    Qs[d + 0][row] = qv.x; Qs[d + 1][row] = qv.y;
    Qs[d + 2][row] = qv.z; Qs[d + 3][row] = qv.w;
    Ks[d + 0][row] = kv.x; Ks[d + 1][row] = kv.y;
    Ks[d + 2][row] = kv.z; Ks[d + 3][row] = kv.w;
  }
  __syncthreads();
  int tx = tid & 15, ty = tid >> 4;
  float acc[4][4] = {};
#pragma unroll 8
  for (int kk = 0; kk < 64; ++kk) {
    float4 a4 = *(const float4*)&Qs[kk][ty << 2];
    float4 b4 = *(const float4*)&Ks[kk][tx << 2];
    float a[4] = {a4.x, a4.y, a4.z, a4.w};
    float b[4] = {b4.x, b4.y, b4.z, b4.w};
#pragma unroll
    for (int ii = 0; ii < 4; ++ii)
#pragma unroll
      for (int jj = 0; jj < 4; ++jj) acc[ii][jj] += a[ii] * b[jj];
  }
#pragma unroll
  for (int ii = 0; ii < 4; ++ii) {
    int gi = (b * TT) + i0 + (ty << 2) + ii;
    float4 o;
    o.x = fmaxf(acc[ii][0] * 0.125f, 0.f);
    o.y = fmaxf(acc[ii][1] * 0.125f, 0.f);
    o.z = fmaxf(acc[ii][2] * 0.125f, 0.f);
    o.w = fmaxf(acc[ii][3] * 0.125f, 0.f);
    *(float4*)(Sbuf + (size_t)gi * TT + j0 + (tx << 2)) = o;
  }
}

// ---------------------------------------------------------------------------
// Column-wise exclusive prefix scan over rows (chunked, two passes).
// ---------------------------------------------------------------------------
__global__ __launch_bounds__(256) void scan_partial(
    const float* __restrict__ Sbuf, float* __restrict__ partials) {
  int j = blockIdx.x * 256 + threadIdx.x;
  int chunk = blockIdx.y, b = blockIdx.z;
  int r0 = chunk * 128;
  const float* base = Sbuf + (size_t)(b * TT + r0) * TT + j;
  float sum = 0.f;
  for (int rr = 0; rr < 128; ++rr) {
    int r = r0 + rr;
    float v = (j >= 1 && j < r) ? base[(size_t)rr * TT] : 0.f;
    sum += v;
  }
  partials[(size_t)(b * 16 + chunk) * TT + j] = sum;
}

__global__ __launch_bounds__(256) void scan_write(
    float* __restrict__ Sbuf, const float* __restrict__ partials) {
  int j = blockIdx.x * 256 + threadIdx.x;
  int chunk = blockIdx.y, b = blockIdx.z;
  float run = 0.f;
  for (int c = 0; c < chunk; ++c) run += partials[(size_t)(b * 16 + c) * TT + j];
  int r0 = chunk * 128;
  float* base = Sbuf + (size_t)(b * TT + r0) * TT + j;
  for (int rr = 0; rr < 128; ++rr) {
    int r = r0 + rr;
    float v = (j >= 1 && j < r) ? base[(size_t)rr * TT] : 0.f;
    base[(size_t)rr * TT] = run;
    run += v;
  }
}

// ---------------------------------------------------------------------------
// FF_sum[b,i] = sum_j clip(FF[b,i,j], 0, 1)
// ---------------------------------------------------------------------------
__global__ __launch_bounds__(256) void ffsum_kernel(
    const float* __restrict__ FF, float* __restrict__ ffsum) {
  int i = blockIdx.x, b = blockIdx.y;
  const float4* row = (const float4*)(FF + (size_t)(b * TT + i) * TT);
  float s = 0.f;
  for (int r = threadIdx.x; r < TT / 4; r += 256) {
    float4 v = row[r];
    s += fminf(fmaxf(v.x, 0.f), 1.f) + fminf(fmaxf(v.y, 0.f), 1.f) +
         fminf(fmaxf(v.z, 0.f), 1.f) + fminf(fmaxf(v.w, 0.f), 1.f);
  }
#pragma unroll
  for (int o = 1; o < 64; o <<= 1) s += __shfl_xor(s, o);
  __shared__ float ws[4];
  if ((threadIdx.x & 63) == 0) ws[threadIdx.x >> 6] = s;
  __syncthreads();
  if (threadIdx.x == 0) ffsum[b * TT + i] = ws[0] + ws[1] + ws[2] + ws[3];
}

// ---------------------------------------------------------------------------
// Pack qkv fp32 -> head-major bf16 Q,K and transposed V (Vt[bh][d][t]).
// ---------------------------------------------------------------------------
__global__ __launch_bounds__(256) void prep_qkv(
    const float* __restrict__ qkv, unsigned short* __restrict__ Qb,
    unsigned short* __restrict__ Kb, unsigned short* __restrict__ Vt) {
  int h = blockIdx.x, tt = blockIdx.y, b = blockIdx.z;
  int t0 = tt * 64;
  int bh = b * NH + h;
  __shared__ float vt[64][65];
  const float* base = qkv + (size_t)(b * TT + t0) * N3 + h * HD;
#pragma unroll
  for (int rep = 0; rep < 4; ++rep) {
    int idx = threadIdx.x + rep * 256;
    int r = idx >> 4, c = (idx & 15) << 2;
    float4 qv = *(const float4*)(base + (size_t)r * N3 + c);
    float4 kv = *(const float4*)(base + (size_t)r * N3 + CC + c);
    float4 vv = *(const float4*)(base + (size_t)r * N3 + 2 * CC + c);
    ushort4 qo; qo.x = f2b(qv.x); qo.y = f2b(qv.y); qo.z = f2b(qv.z); qo.w = f2b(qv.w);
    ushort4 ko; ko.x = f2b(kv.x); ko.y = f2b(kv.y); ko.z = f2b(kv.z); ko.w = f2b(kv.w);
    *(ushort4*)(Qb + ((size_t)bh * TT + t0 + r) * HD + c) = qo;
    *(ushort4*)(Kb + ((size_t)bh * TT + t0 + r) * HD + c) = ko;
    vt[c + 0][r] = vv.x; vt[c + 1][r] = vv.y;
    vt[c + 2][r] = vv.z; vt[c + 3][r] = vv.w;
  }
  __syncthreads();
#pragma unroll
  for (int rep = 0; rep < 4; ++rep) {
    int idx = threadIdx.x + rep * 256;
    int d = idx >> 4, t4 = (idx & 15) << 2;
    ushort4 vo;
    vo.x = f2b(vt[d][t4 + 0]); vo.y = f2b(vt[d][t4 + 1]);
    vo.z = f2b(vt[d][t4 + 2]); vo.w = f2b(vt[d][t4 + 3]);
    *(ushort4*)(Vt + ((size_t)bh * HD + d) * TT + t0 + t4) = vo;
  }
}

// ---------------------------------------------------------------------------
// bf16 MFMA flash attention, fp32 -FF shift. One wave owns 16 q-rows.
// Block = 4 waves with IDENTICAL k-range (i0 = g4*64 + wave*16, ktend = g4).
// Per-wave software pipeline: K frags loaded one tile ahead (load-at-bottom);
// V/FF issued at tile top, consumed after QK / at softmax. No __syncthreads.
// ---------------------------------------------------------------------------
__global__ __launch_bounds__(256, 3) void attn_mfma(
    const unsigned short* __restrict__ Qb, const unsigned short* __restrict__ Kb,
    const unsigned short* __restrict__ Vt, const float* __restrict__ FF,
    float* __restrict__ yh) {
  int g4 = 31 - blockIdx.x, h = blockIdx.y, b = blockIdx.z;
  int wave = threadIdx.x >> 6, lane = threadIdx.x & 63;
  int lr = lane & 15, lg = lane >> 4;
  int i0 = g4 * 64 + wave * 16;
  int bh = b * NH + h;
  const unsigned short* Qh = Qb + (size_t)bh * TT * HD;
  const unsigned short* Kh = Kb + (size_t)bh * TT * HD;
  const unsigned short* Vh = Vt + (size_t)bh * HD * TT;

  __shared__ __align__(16) unsigned short Plds[4][16][80];

  // Q fragments: lane holds Q[i0 + lr][ks*32 + lg*8 .. +7]
  bf16x8 qf[2];
#pragma unroll
  for (int ks = 0; ks < 2; ++ks)
    qf[ks] = *(const bf16x8*)(Qh + (size_t)(i0 + lr) * HD + ks * 32 + lg * 8);

  f32x4 acc[4];
  float mrun[4], lrun[4];
#pragma unroll
  for (int q = 0; q < 4; ++q) {
    acc[q] = (f32x4){0.f, 0.f, 0.f, 0.f};
    mrun[q] = -1e30f;
    lrun[q] = 0.f;
  }

  int ktend = g4;
  // Prefetch K fragments for tile 0
  bf16x8 kf[4][2];
#pragma unroll
  for (int nj = 0; nj < 4; ++nj) {
    kf[nj][0] = *(const bf16x8*)(Kh + (size_t)(nj * 16 + lr) * HD + lg * 8);
    kf[nj][1] = *(const bf16x8*)(Kh + (size_t)(nj * 16 + lr) * HD + 32 + lg * 8);
  }

  for (int kt = 0; kt <= ktend; ++kt) {
    int j0 = kt * 64;
    // Issue V loads for this tile (consumed after softmax)
    bf16x8 vf[4][2];
#pragma unroll
    for (int nd = 0; nd < 4; ++nd)
#pragma unroll
      for (int ks = 0; ks < 2; ++ks)
        vf[nd][ks] = *(const bf16x8*)(Vh + (size_t)(nd * 16 + lr) * TT + j0 + ks * 32 + lg * 8);
    // Issue FF loads for this tile (consumed at softmax)
    const float* ffb = FF + ((size_t)(b * TT) + i0 + lg * 4) * TT + j0 + lr;
    float ff[4][4];
#pragma unroll
    for (int r = 0; r < 4; ++r)
#pragma unroll
      for (int nj = 0; nj < 4; ++nj)
        ff[r][nj] = ffb[(size_t)r * TT + nj * 16];

    // QK^T using prefetched kf: S D-layout row=lg*4+r, col=lr
    f32x4 s[4];
#pragma unroll
    for (int nj = 0; nj < 4; ++nj) {
      f32x4 z = (f32x4){0.f, 0.f, 0.f, 0.f};
      z = __builtin_amdgcn_mfma_f32_16x16x32_bf16(qf[0], kf[nj][0], z, 0, 0, 0);
      s[nj] = __builtin_amdgcn_mfma_f32_16x16x32_bf16(qf[1], kf[nj][1], z, 0, 0, 0);
    }
    // Prefetch K fragments for next tile (covered by softmax+PV below)
    if (kt < ktend) {
      int jn = j0 + 64;
#pragma unroll
      for (int nj = 0; nj < 4; ++nj) {
        kf[nj][0] = *(const bf16x8*)(Kh + (size_t)(jn + nj * 16 + lr) * HD + lg * 8);
        kf[nj][1] = *(const bf16x8*)(Kh + (size_t)(jn + nj * 16 + lr) * HD + 32 + lg * 8);
      }
    }

    // ---- logits + online softmax (rows i0+lg*4+r) ----
    int ibase = i0 + lg * 4;
    float mt[4] = {-1e30f, -1e30f, -1e30f, -1e30f};
#pragma unroll
    for (int nj = 0; nj < 4; ++nj) {
#pragma unroll
      for (int r = 0; r < 4; ++r) {
        int ig = ibase + r, jg = j0 + nj * 16 + lr;
        float lv = (jg <= ig) ? s[nj][r] * 0.125f - ff[r][nj] : -1e30f;
        s[nj][r] = lv;
        mt[r] = fmaxf(mt[r], lv);
      }
    }
#pragma unroll
    for (int r = 0; r < 4; ++r) {
      mt[r] = fmaxf(mt[r], __shfl_xor(mt[r], 1));
      mt[r] = fmaxf(mt[r], __shfl_xor(mt[r], 2));
      mt[r] = fmaxf(mt[r], __shfl_xor(mt[r], 4));
      mt[r] = fmaxf(mt[r], __shfl_xor(mt[r], 8));
      float mnew = fmaxf(mrun[r], mt[r]);
      float scl = __expf(mrun[r] - mnew);
      mrun[r] = mnew;
      lrun[r] *= scl;
#pragma unroll
      for (int nd = 0; nd < 4; ++nd) acc[nd][r] *= scl;
    }
    float ps[4] = {0.f, 0.f, 0.f, 0.f};
#pragma unroll
    for (int nj = 0; nj < 4; ++nj)
#pragma unroll
      for (int r = 0; r < 4; ++r) {
        float p = __expf(s[nj][r] - mrun[r]);
        ps[r] += p;
        Plds[wave][lg * 4 + r][nj * 16 + lr] = f2b(p);
      }
#pragma unroll
    for (int r = 0; r < 4; ++r) {
      ps[r] += __shfl_xor(ps[r], 1);
      ps[r] += __shfl_xor(ps[r], 2);
      ps[r] += __shfl_xor(ps[r], 4);
      ps[r] += __shfl_xor(ps[r], 8);
      lrun[r] += ps[r];
    }

    // ---- PV: O[i][d] += P[i][j] V[j][d] ----
    bf16x8 pa[2];
    pa[0] = *(const bf16x8*)&Plds[wave][lr][lg * 8];
    pa[1] = *(const bf16x8*)&Plds[wave][lr][32 + lg * 8];
#pragma unroll
    for (int nd = 0; nd < 4; ++nd) {
      acc[nd] = __builtin_amdgcn_mfma_f32_16x16x32_bf16(pa[0], vf[nd][0], acc[nd], 0, 0, 0);
      acc[nd] = __builtin_amdgcn_mfma_f32_16x16x32_bf16(pa[1], vf[nd][1], acc[nd], 0, 0, 0);
    }
  }

  // ---- epilogue ----
#pragma unroll
  for (int r = 0; r < 4; ++r) {
    float inv = 1.f / lrun[r];
    int ig = i0 + lg * 4 + r;
    float* ob = yh + (size_t)(b * TT + ig) * CC + h * HD;
#pragma unroll
    for (int nd = 0; nd < 4; ++nd)
      ob[nd * 16 + lr] = acc[nd][r] * inv;
  }
}

// ---------------------------------------------------------------------------
// M[0,b,i,j] = i - ffsum[b,j]
// ---------------------------------------------------------------------------
__global__ __launch_bounds__(256) void m_kernel(
    const float* __restrict__ ffsum, float* __restrict__ Mout) {
  int idx = blockIdx.x * blockDim.x + threadIdx.x;
  int stride = gridDim.x * blockDim.x;
  for (; idx < M_ELEMS; idx += stride) {
    int j = idx & (TT - 1);
    int i = (idx >> 11) & (TT - 1);
    int b = idx >> 22;
    Mout[idx] = (float)i - ffsum[(b << 11) + j];
  }
}

// ---------------------------------------------------------------------------
extern "C" void kernel_launch(void* const* d_in, const int* in_sizes, int n_in,
                              void* d_out, int out_size, void* d_ws, size_t ws_size,
                              hipStream_t stream) {
  const float* x      = (const float*)d_in[0];
  const float* w_attn = (const float*)d_in[1];
  const float* b_attn = (const float*)d_in[2];
  const float* w_proj = (const float*)d_in[3];
  const float* b_proj = (const float*)d_in[4];

  float* y    = (float*)d_out;          // [B,T,C]
  float* Mreg = y + Y_ELEMS;            // [B,T,T]: S0 -> FF (scratch) -> M (final)

  float* ws = (float*)d_ws;
  float* qkv = ws;                                 // 9,437,184 f32 (37.7 MB)
  float* yh  = ws;                                 // aliases qkv (qkv dead before attn writes yh)
  float* partials = qkv + (size_t)BB * TT * N3;    // B*16*T
  float* ffsum    = partials + BB * 16 * TT;       // B*T
  unsigned short* Qb = (unsigned short*)(ffsum + BB * TT);
  unsigned short* Kb = Qb + (size_t)BB * NH * TT * HD;   // 3,145,728 each
  unsigned short* Vt = Kb + (size_t)BB * NH * TT * HD;
  // total ws usage ~= 54.3 MB

  // 1. QKV = x @ w_attn + b_attn  (fp32 — head-0 q,k feed the FF cumsum)
  sgemm_bias<<<dim3(64, 36), 256, 0, stream>>>(x, w_attn, b_attn, qkv, BB * TT, N3, CC);
  // 2. head-0 scores (relu'd, fp32) into Mreg
  score0_kernel<<<dim3(32, 32, BB), 256, 0, stream>>>(qkv, Mreg);
  // 3. column-wise exclusive scan (in place): Mreg = FF
  scan_partial<<<dim3(8, 16, BB), 256, 0, stream>>>(Mreg, partials);
  scan_write<<<dim3(8, 16, BB), 256, 0, stream>>>(Mreg, partials);
  // 4. FF_sum
  ffsum_kernel<<<dim3(TT, BB), 256, 0, stream>>>(Mreg, ffsum);
  // 5. pack to bf16 head-major Q,K + transposed V (last reader of qkv)
  prep_qkv<<<dim3(NH, 32, BB), 256, 0, stream>>>(qkv, Qb, Kb, Vt);
  // 6. MFMA flash attention (reads FF from Mreg; writes yh over dead qkv)
  attn_mfma<<<dim3(32, NH, BB), 256, 0, stream>>>(Qb, Kb, Vt, Mreg, yh);
  // 7. M output (overwrites Mreg AFTER attention consumed FF)
  m_kernel<<<4096, 256, 0, stream>>>(ffsum, Mreg);
  // 8. y = yh @ w_proj + b_proj
  sgemm_bias<<<dim3(64, 12), 256, 0, stream>>>(yh, w_proj, b_proj, y, BB * TT, CC, CC);
}

// Round 4
// 423.898 us; speedup vs baseline: 3.5017x; 1.2268x over previous
//
#include <hip/hip_runtime.h>
#include <cstddef>

// Problem constants
#define TT 2048
#define BB 2
#define CC 768
#define NH 12
#define HD 64
#define N3 2304          // 3*NH*HD
#define Y_ELEMS (BB*TT*CC)          // 3145728
#define M_ELEMS (BB*TT*TT)          // 8388608

typedef __attribute__((ext_vector_type(8))) short bf16x8;
typedef __attribute__((ext_vector_type(4))) float f32x4;

__device__ inline unsigned short f2b(float f) {
  union { float f; unsigned u; } v; v.f = f;
  unsigned r = (v.u + 0x7FFFu + ((v.u >> 16) & 1u)) >> 16;
  return (unsigned short)r;
}

// ---------------------------------------------------------------------------
// pack x (fp32) -> xb (bf16). 8 elems/thread.
// ---------------------------------------------------------------------------
__global__ __launch_bounds__(256) void pack_x(
    const float* __restrict__ x, unsigned short* __restrict__ xb) {
  size_t i = ((size_t)blockIdx.x * 256 + threadIdx.x) * 8;
  float4 a = *(const float4*)(x + i);
  float4 b = *(const float4*)(x + i + 4);
  ushort4 o0, o1;
  o0.x = f2b(a.x); o0.y = f2b(a.y); o0.z = f2b(a.z); o0.w = f2b(a.w);
  o1.x = f2b(b.x); o1.y = f2b(b.y); o1.z = f2b(b.z); o1.w = f2b(b.w);
  *(ushort4*)(xb + i) = o0;
  *(ushort4*)(xb + i + 4) = o1;
}

// ---------------------------------------------------------------------------
// W [768][N] fp32 -> WT [N][768] bf16 (transposed pack). Block=(kt,nt) 64x64.
// ---------------------------------------------------------------------------
__global__ __launch_bounds__(256) void transpose_pack(
    const float* __restrict__ W, unsigned short* __restrict__ WT, int N) {
  __shared__ float tile[64][65];
  int kt = blockIdx.x, nt = blockIdx.y;
  int tid = threadIdx.x;
  int r = tid >> 4, c4 = (tid & 15) << 2;
#pragma unroll
  for (int rep = 0; rep < 4; ++rep) {
    int row = rep * 16 + r;
    float4 v = *(const float4*)(W + (size_t)(kt * 64 + row) * N + nt * 64 + c4);
    tile[row][c4 + 0] = v.x; tile[row][c4 + 1] = v.y;
    tile[row][c4 + 2] = v.z; tile[row][c4 + 3] = v.w;
  }
  __syncthreads();
#pragma unroll
  for (int rep = 0; rep < 4; ++rep) {
    int nrow = rep * 16 + r;
    ushort4 o;
    o.x = f2b(tile[c4 + 0][nrow]); o.y = f2b(tile[c4 + 1][nrow]);
    o.z = f2b(tile[c4 + 2][nrow]); o.w = f2b(tile[c4 + 3][nrow]);
    *(ushort4*)(WT + (size_t)(nt * 64 + nrow) * CC + kt * 64 + c4) = o;
  }
}

// ---------------------------------------------------------------------------
// bf16 MFMA GEMM: qkv = xb @ wbT^T + b_attn, written DIRECTLY into packed
// Qb[bh][t][d], Kb[bh][t][d], Vt[bh][d][t] (V transposed via LDS).
// Grid (32 mtiles of 128, 36 ntiles of 64). 4 waves, each 32 rows x 64 cols.
// ---------------------------------------------------------------------------
__global__ __launch_bounds__(256, 2) void gemm_qkv_bf16(
    const unsigned short* __restrict__ xb, const unsigned short* __restrict__ wbT,
    const float* __restrict__ b_attn,
    unsigned short* __restrict__ Qb, unsigned short* __restrict__ Kb,
    unsigned short* __restrict__ Vt) {
  __shared__ __align__(16) unsigned short Vlds[128][72];
  int mt = blockIdx.x, nt = blockIdx.y;
  int sec = nt / NH, h = nt % NH;
  int wave = threadIdx.x >> 6, lane = threadIdx.x & 63;
  int lr = lane & 15, lg = lane >> 4;
  int m0 = mt * 128 + wave * 32;
  int n0 = nt * 64;
  const unsigned short* Ab = xb + (size_t)m0 * CC;
  const unsigned short* Bb = wbT + (size_t)n0 * CC;

  f32x4 acc[2][4];
#pragma unroll
  for (int mi = 0; mi < 2; ++mi)
#pragma unroll
    for (int nj = 0; nj < 4; ++nj) acc[mi][nj] = (f32x4){0.f, 0.f, 0.f, 0.f};

#pragma unroll
  for (int ks = 0; ks < 24; ++ks) {
    int k0 = ks * 32;
    bf16x8 af[2], bf[4];
#pragma unroll
    for (int mi = 0; mi < 2; ++mi)
      af[mi] = *(const bf16x8*)(Ab + (size_t)(mi * 16 + lr) * CC + k0 + lg * 8);
#pragma unroll
    for (int nj = 0; nj < 4; ++nj)
      bf[nj] = *(const bf16x8*)(Bb + (size_t)(nj * 16 + lr) * CC + k0 + lg * 8);
#pragma unroll
    for (int nj = 0; nj < 4; ++nj)
#pragma unroll
      for (int mi = 0; mi < 2; ++mi)
        acc[mi][nj] = __builtin_amdgcn_mfma_f32_16x16x32_bf16(af[mi], bf[nj], acc[mi][nj], 0, 0, 0);
  }

  int b = m0 >> 11;
  int bh = b * NH + h;
  float bias[4];
#pragma unroll
  for (int nj = 0; nj < 4; ++nj) bias[nj] = b_attn[n0 + nj * 16 + lr];

  if (sec < 2) {
    unsigned short* Out = (sec == 0 ? Qb : Kb) + (size_t)bh * TT * HD;
    int tbase = (m0 & 2047) + lg * 4;
#pragma unroll
    for (int mi = 0; mi < 2; ++mi)
#pragma unroll
      for (int r = 0; r < 4; ++r) {
        int t = tbase + mi * 16 + r;
#pragma unroll
        for (int nj = 0; nj < 4; ++nj)
          Out[(size_t)t * HD + nj * 16 + lr] = f2b(acc[mi][nj][r] + bias[nj]);
      }
  } else {
    int tl = wave * 32 + lg * 4;
#pragma unroll
    for (int mi = 0; mi < 2; ++mi)
#pragma unroll
      for (int r = 0; r < 4; ++r)
#pragma unroll
        for (int nj = 0; nj < 4; ++nj)
          Vlds[tl + mi * 16 + r][nj * 16 + lr] = f2b(acc[mi][nj][r] + bias[nj]);
    __syncthreads();
    int d = threadIdx.x & 63, tc = threadIdx.x >> 6;
    int tblk = (mt * 128) & 2047;
    unsigned short* Ov = Vt + ((size_t)bh * HD + d) * TT + tblk + tc * 32;
#pragma unroll
    for (int i8 = 0; i8 < 4; ++i8) {
      ushort4 o0, o1;
      o0.x = Vlds[tc * 32 + i8 * 8 + 0][d]; o0.y = Vlds[tc * 32 + i8 * 8 + 1][d];
      o0.z = Vlds[tc * 32 + i8 * 8 + 2][d]; o0.w = Vlds[tc * 32 + i8 * 8 + 3][d];
      o1.x = Vlds[tc * 32 + i8 * 8 + 4][d]; o1.y = Vlds[tc * 32 + i8 * 8 + 5][d];
      o1.z = Vlds[tc * 32 + i8 * 8 + 6][d]; o1.w = Vlds[tc * 32 + i8 * 8 + 7][d];
      *(ushort4*)(Ov + i8 * 8) = o0;
      *(ushort4*)(Ov + i8 * 8 + 4) = o1;
    }
  }
}

// ---------------------------------------------------------------------------
// bf16 MFMA GEMM: y = yhb @ wpT^T + b_proj (fp32 out). Grid (32, 12).
// ---------------------------------------------------------------------------
__global__ __launch_bounds__(256, 2) void gemm_proj_bf16(
    const unsigned short* __restrict__ yhb, const unsigned short* __restrict__ wpT,
    const float* __restrict__ b_proj, float* __restrict__ y) {
  int mt = blockIdx.x, nt = blockIdx.y;
  int wave = threadIdx.x >> 6, lane = threadIdx.x & 63;
  int lr = lane & 15, lg = lane >> 4;
  int m0 = mt * 128 + wave * 32;
  int n0 = nt * 64;
  const unsigned short* Ab = yhb + (size_t)m0 * CC;
  const unsigned short* Bb = wpT + (size_t)n0 * CC;

  f32x4 acc[2][4];
#pragma unroll
  for (int mi = 0; mi < 2; ++mi)
#pragma unroll
    for (int nj = 0; nj < 4; ++nj) acc[mi][nj] = (f32x4){0.f, 0.f, 0.f, 0.f};

#pragma unroll
  for (int ks = 0; ks < 24; ++ks) {
    int k0 = ks * 32;
    bf16x8 af[2], bf[4];
#pragma unroll
    for (int mi = 0; mi < 2; ++mi)
      af[mi] = *(const bf16x8*)(Ab + (size_t)(mi * 16 + lr) * CC + k0 + lg * 8);
#pragma unroll
    for (int nj = 0; nj < 4; ++nj)
      bf[nj] = *(const bf16x8*)(Bb + (size_t)(nj * 16 + lr) * CC + k0 + lg * 8);
#pragma unroll
    for (int nj = 0; nj < 4; ++nj)
#pragma unroll
      for (int mi = 0; mi < 2; ++mi)
        acc[mi][nj] = __builtin_amdgcn_mfma_f32_16x16x32_bf16(af[mi], bf[nj], acc[mi][nj], 0, 0, 0);
  }

  float bias[4];
#pragma unroll
  for (int nj = 0; nj < 4; ++nj) bias[nj] = b_proj[n0 + nj * 16 + lr];
#pragma unroll
  for (int mi = 0; mi < 2; ++mi)
#pragma unroll
    for (int r = 0; r < 4; ++r) {
      int m = m0 + mi * 16 + lg * 4 + r;
#pragma unroll
      for (int nj = 0; nj < 4; ++nj)
        y[(size_t)m * CC + n0 + nj * 16 + lr] = acc[mi][nj][r] + bias[nj];
    }
}

// ---------------------------------------------------------------------------
// fp32 GEMM for head-0 q,k only (precision-critical for the FF cumsum):
// q0/k0 [B*T][64] = x @ w_attn[:, sec*768 .. sec*768+63] + bias.
// Grid (64 mtiles, 2 sec).
// ---------------------------------------------------------------------------
__global__ __launch_bounds__(256) void sgemm_qk0(
    const float* __restrict__ x, const float* __restrict__ w_attn,
    const float* __restrict__ b_attn, float* __restrict__ q0,
    float* __restrict__ k0) {
  __shared__ float As[16][64];
  __shared__ float Bs[16][64];
  int sec = blockIdx.y;
  const float* Bw = w_attn + sec * CC;
  float* Out = sec ? k0 : q0;
  int tid = threadIdx.x;
  int tx = tid & 15, ty = tid >> 4;
  int m0 = blockIdx.x * 64;

  int arow = tid >> 2;
  int acol4 = (tid & 3) << 2;
  int brow = tid >> 4;
  int bcol4 = (tid & 15) << 2;

  const float* Aptr = x + (size_t)(m0 + arow) * CC + acol4;
  const float* Bptr = Bw + (size_t)brow * N3 + bcol4;

  float acc[4][4] = {};

  for (int k0_ = 0; k0_ < CC; k0_ += 16) {
    float4 av = *(const float4*)(Aptr + k0_);
    float4 bv = *(const float4*)(Bptr + (size_t)k0_ * N3);
    As[acol4 + 0][arow] = av.x;
    As[acol4 + 1][arow] = av.y;
    As[acol4 + 2][arow] = av.z;
    As[acol4 + 3][arow] = av.w;
    *(float4*)&Bs[brow][bcol4] = bv;
    __syncthreads();
#pragma unroll
    for (int kk = 0; kk < 16; ++kk) {
      float4 a4 = *(const float4*)&As[kk][ty << 2];
      float4 b4 = *(const float4*)&Bs[kk][tx << 2];
      float a[4] = {a4.x, a4.y, a4.z, a4.w};
      float b[4] = {b4.x, b4.y, b4.z, b4.w};
#pragma unroll
      for (int ii = 0; ii < 4; ++ii)
#pragma unroll
        for (int jj = 0; jj < 4; ++jj) acc[ii][jj] += a[ii] * b[jj];
    }
    __syncthreads();
  }

  float4 bv = *(const float4*)(b_attn + sec * CC + (tx << 2));
#pragma unroll
  for (int ii = 0; ii < 4; ++ii) {
    int m = m0 + (ty << 2) + ii;
    float4 o;
    o.x = acc[ii][0] + bv.x;
    o.y = acc[ii][1] + bv.y;
    o.z = acc[ii][2] + bv.z;
    o.w = acc[ii][3] + bv.w;
    *(float4*)(Out + (size_t)m * HD + (tx << 2)) = o;
  }
}

// ---------------------------------------------------------------------------
// Head-0 scores (fp32): Sbuf[b,i,j] = relu(dot(q0[b,i],k0[b,j]) / 8),
// lower-triangle tiles only.
// ---------------------------------------------------------------------------
__global__ __launch_bounds__(256) void score0_kernel(
    const float* __restrict__ q0, const float* __restrict__ k0,
    float* __restrict__ Sbuf) {
  int it = blockIdx.x, jt = blockIdx.y, b = blockIdx.z;
  if (jt > it) return;
  __shared__ float Qs[64][64];
  __shared__ float Ks[64][64];
  int tid = threadIdx.x;
  int row = tid >> 2;
  int dq = (tid & 3) << 2;
  int i0 = it * 64, j0 = jt * 64;
  const float* qb = q0 + (size_t)((b * TT) + i0 + row) * HD;
  const float* kb = k0 + (size_t)((b * TT) + j0 + row) * HD;
#pragma unroll
  for (int rep = 0; rep < 4; ++rep) {
    int d = dq + rep * 16;
    float4 qv = *(const float4*)(qb + d);
    float4 kv = *(const float4*)(kb + d);
    Qs[d + 0][row] = qv.x; Qs[d + 1][row] = qv.y;
    Qs[d + 2][row] = qv.z; Qs[d + 3][row] = qv.w;
    Ks[d + 0][row] = kv.x; Ks[d + 1][row] = kv.y;
    Ks[d + 2][row] = kv.z; Ks[d + 3][row] = kv.w;
  }
  __syncthreads();
  int tx = tid & 15, ty = tid >> 4;
  float acc[4][4] = {};
#pragma unroll 8
  for (int kk = 0; kk < 64; ++kk) {
    float4 a4 = *(const float4*)&Qs[kk][ty << 2];
    float4 b4 = *(const float4*)&Ks[kk][tx << 2];
    float a[4] = {a4.x, a4.y, a4.z, a4.w};
    float b[4] = {b4.x, b4.y, b4.z, b4.w};
#pragma unroll
    for (int ii = 0; ii < 4; ++ii)
#pragma unroll
      for (int jj = 0; jj < 4; ++jj) acc[ii][jj] += a[ii] * b[jj];
  }
#pragma unroll
  for (int ii = 0; ii < 4; ++ii) {
    int gi = (b * TT) + i0 + (ty << 2) + ii;
    float4 o;
    o.x = fmaxf(acc[ii][0] * 0.125f, 0.f);
    o.y = fmaxf(acc[ii][1] * 0.125f, 0.f);
    o.z = fmaxf(acc[ii][2] * 0.125f, 0.f);
    o.w = fmaxf(acc[ii][3] * 0.125f, 0.f);
    *(float4*)(Sbuf + (size_t)gi * TT + j0 + (tx << 2)) = o;
  }
}

// ---------------------------------------------------------------------------
// Column-wise exclusive prefix scan over rows (chunked, two passes).
// ---------------------------------------------------------------------------
__global__ __launch_bounds__(256) void scan_partial(
    const float* __restrict__ Sbuf, float* __restrict__ partials) {
  int j = blockIdx.x * 256 + threadIdx.x;
  int chunk = blockIdx.y, b = blockIdx.z;
  int r0 = chunk * 128;
  const float* base = Sbuf + (size_t)(b * TT + r0) * TT + j;
  float sum = 0.f;
  for (int rr = 0; rr < 128; ++rr) {
    int r = r0 + rr;
    float v = (j >= 1 && j < r) ? base[(size_t)rr * TT] : 0.f;
    sum += v;
  }
  partials[(size_t)(b * 16 + chunk) * TT + j] = sum;
}

__global__ __launch_bounds__(256) void scan_write(
    float* __restrict__ Sbuf, const float* __restrict__ partials) {
  int j = blockIdx.x * 256 + threadIdx.x;
  int chunk = blockIdx.y, b = blockIdx.z;
  float run = 0.f;
  for (int c = 0; c < chunk; ++c) run += partials[(size_t)(b * 16 + c) * TT + j];
  int r0 = chunk * 128;
  float* base = Sbuf + (size_t)(b * TT + r0) * TT + j;
  for (int rr = 0; rr < 128; ++rr) {
    int r = r0 + rr;
    float v = (j >= 1 && j < r) ? base[(size_t)rr * TT] : 0.f;
    base[(size_t)rr * TT] = run;
    run += v;
  }
}

// ---------------------------------------------------------------------------
// FF_sum[b,i] = sum_j clip(FF[b,i,j], 0, 1)
// ---------------------------------------------------------------------------
__global__ __launch_bounds__(256) void ffsum_kernel(
    const float* __restrict__ FF, float* __restrict__ ffsum) {
  int i = blockIdx.x, b = blockIdx.y;
  const float4* row = (const float4*)(FF + (size_t)(b * TT + i) * TT);
  float s = 0.f;
  for (int r = threadIdx.x; r < TT / 4; r += 256) {
    float4 v = row[r];
    s += fminf(fmaxf(v.x, 0.f), 1.f) + fminf(fmaxf(v.y, 0.f), 1.f) +
         fminf(fmaxf(v.z, 0.f), 1.f) + fminf(fmaxf(v.w, 0.f), 1.f);
  }
#pragma unroll
  for (int o = 1; o < 64; o <<= 1) s += __shfl_xor(s, o);
  __shared__ float ws[4];
  if ((threadIdx.x & 63) == 0) ws[threadIdx.x >> 6] = s;
  __syncthreads();
  if (threadIdx.x == 0) ffsum[b * TT + i] = ws[0] + ws[1] + ws[2] + ws[3];
}

// ---------------------------------------------------------------------------
// bf16 MFMA flash attention, fp32 -FF shift. One wave owns 16 q-rows.
// Block = 4 waves with IDENTICAL k-range. K frags prefetched one tile ahead.
// Epilogue writes bf16 yhb.
// ---------------------------------------------------------------------------
__global__ __launch_bounds__(256, 3) void attn_mfma(
    const unsigned short* __restrict__ Qb, const unsigned short* __restrict__ Kb,
    const unsigned short* __restrict__ Vt, const float* __restrict__ FF,
    unsigned short* __restrict__ yhb) {
  int g4 = 31 - blockIdx.x, h = blockIdx.y, b = blockIdx.z;
  int wave = threadIdx.x >> 6, lane = threadIdx.x & 63;
  int lr = lane & 15, lg = lane >> 4;
  int i0 = g4 * 64 + wave * 16;
  int bh = b * NH + h;
  const unsigned short* Qh = Qb + (size_t)bh * TT * HD;
  const unsigned short* Kh = Kb + (size_t)bh * TT * HD;
  const unsigned short* Vh = Vt + (size_t)bh * HD * TT;

  __shared__ __align__(16) unsigned short Plds[4][16][80];

  bf16x8 qf[2];
#pragma unroll
  for (int ks = 0; ks < 2; ++ks)
    qf[ks] = *(const bf16x8*)(Qh + (size_t)(i0 + lr) * HD + ks * 32 + lg * 8);

  f32x4 acc[4];
  float mrun[4], lrun[4];
#pragma unroll
  for (int q = 0; q < 4; ++q) {
    acc[q] = (f32x4){0.f, 0.f, 0.f, 0.f};
    mrun[q] = -1e30f;
    lrun[q] = 0.f;
  }

  int ktend = g4;
  bf16x8 kf[4][2];
#pragma unroll
  for (int nj = 0; nj < 4; ++nj) {
    kf[nj][0] = *(const bf16x8*)(Kh + (size_t)(nj * 16 + lr) * HD + lg * 8);
    kf[nj][1] = *(const bf16x8*)(Kh + (size_t)(nj * 16 + lr) * HD + 32 + lg * 8);
  }

  for (int kt = 0; kt <= ktend; ++kt) {
    int j0 = kt * 64;
    bf16x8 vf[4][2];
#pragma unroll
    for (int nd = 0; nd < 4; ++nd)
#pragma unroll
      for (int ks = 0; ks < 2; ++ks)
        vf[nd][ks] = *(const bf16x8*)(Vh + (size_t)(nd * 16 + lr) * TT + j0 + ks * 32 + lg * 8);
    const float* ffb = FF + ((size_t)(b * TT) + i0 + lg * 4) * TT + j0 + lr;
    float ff[4][4];
#pragma unroll
    for (int r = 0; r < 4; ++r)
#pragma unroll
      for (int nj = 0; nj < 4; ++nj)
        ff[r][nj] = ffb[(size_t)r * TT + nj * 16];

    f32x4 s[4];
#pragma unroll
    for (int nj = 0; nj < 4; ++nj) {
      f32x4 z = (f32x4){0.f, 0.f, 0.f, 0.f};
      z = __builtin_amdgcn_mfma_f32_16x16x32_bf16(qf[0], kf[nj][0], z, 0, 0, 0);
      s[nj] = __builtin_amdgcn_mfma_f32_16x16x32_bf16(qf[1], kf[nj][1], z, 0, 0, 0);
    }
    if (kt < ktend) {
      int jn = j0 + 64;
#pragma unroll
      for (int nj = 0; nj < 4; ++nj) {
        kf[nj][0] = *(const bf16x8*)(Kh + (size_t)(jn + nj * 16 + lr) * HD + lg * 8);
        kf[nj][1] = *(const bf16x8*)(Kh + (size_t)(jn + nj * 16 + lr) * HD + 32 + lg * 8);
      }
    }

    int ibase = i0 + lg * 4;
    float mt[4] = {-1e30f, -1e30f, -1e30f, -1e30f};
#pragma unroll
    for (int nj = 0; nj < 4; ++nj) {
#pragma unroll
      for (int r = 0; r < 4; ++r) {
        int ig = ibase + r, jg = j0 + nj * 16 + lr;
        float lv = (jg <= ig) ? s[nj][r] * 0.125f - ff[r][nj] : -1e30f;
        s[nj][r] = lv;
        mt[r] = fmaxf(mt[r], lv);
      }
    }
#pragma unroll
    for (int r = 0; r < 4; ++r) {
      mt[r] = fmaxf(mt[r], __shfl_xor(mt[r], 1));
      mt[r] = fmaxf(mt[r], __shfl_xor(mt[r], 2));
      mt[r] = fmaxf(mt[r], __shfl_xor(mt[r], 4));
      mt[r] = fmaxf(mt[r], __shfl_xor(mt[r], 8));
      float mnew = fmaxf(mrun[r], mt[r]);
      float scl = __expf(mrun[r] - mnew);
      mrun[r] = mnew;
      lrun[r] *= scl;
#pragma unroll
      for (int nd = 0; nd < 4; ++nd) acc[nd][r] *= scl;
    }
    float ps[4] = {0.f, 0.f, 0.f, 0.f};
#pragma unroll
    for (int nj = 0; nj < 4; ++nj)
#pragma unroll
      for (int r = 0; r < 4; ++r) {
        float p = __expf(s[nj][r] - mrun[r]);
        ps[r] += p;
        Plds[wave][lg * 4 + r][nj * 16 + lr] = f2b(p);
      }
#pragma unroll
    for (int r = 0; r < 4; ++r) {
      ps[r] += __shfl_xor(ps[r], 1);
      ps[r] += __shfl_xor(ps[r], 2);
      ps[r] += __shfl_xor(ps[r], 4);
      ps[r] += __shfl_xor(ps[r], 8);
      lrun[r] += ps[r];
    }

    bf16x8 pa[2];
    pa[0] = *(const bf16x8*)&Plds[wave][lr][lg * 8];
    pa[1] = *(const bf16x8*)&Plds[wave][lr][32 + lg * 8];
#pragma unroll
    for (int nd = 0; nd < 4; ++nd) {
      acc[nd] = __builtin_amdgcn_mfma_f32_16x16x32_bf16(pa[0], vf[nd][0], acc[nd], 0, 0, 0);
      acc[nd] = __builtin_amdgcn_mfma_f32_16x16x32_bf16(pa[1], vf[nd][1], acc[nd], 0, 0, 0);
    }
  }

#pragma unroll
  for (int r = 0; r < 4; ++r) {
    float inv = 1.f / lrun[r];
    int ig = i0 + lg * 4 + r;
    unsigned short* ob = yhb + (size_t)(b * TT + ig) * CC + h * HD;
#pragma unroll
    for (int nd = 0; nd < 4; ++nd)
      ob[nd * 16 + lr] = f2b(acc[nd][r] * inv);
  }
}

// ---------------------------------------------------------------------------
// M[0,b,i,j] = i - ffsum[b,j]
// ---------------------------------------------------------------------------
__global__ __launch_bounds__(256) void m_kernel(
    const float* __restrict__ ffsum, float* __restrict__ Mout) {
  int idx = blockIdx.x * blockDim.x + threadIdx.x;
  int stride = gridDim.x * blockDim.x;
  for (; idx < M_ELEMS; idx += stride) {
    int j = idx & (TT - 1);
    int i = (idx >> 11) & (TT - 1);
    int b = idx >> 22;
    Mout[idx] = (float)i - ffsum[(b << 11) + j];
  }
}

// ---------------------------------------------------------------------------
extern "C" void kernel_launch(void* const* d_in, const int* in_sizes, int n_in,
                              void* d_out, int out_size, void* d_ws, size_t ws_size,
                              hipStream_t stream) {
  const float* x      = (const float*)d_in[0];
  const float* w_attn = (const float*)d_in[1];
  const float* b_attn = (const float*)d_in[2];
  const float* w_proj = (const float*)d_in[3];
  const float* b_proj = (const float*)d_in[4];

  float* y    = (float*)d_out;          // [B,T,C]
  float* Mreg = y + Y_ELEMS;            // [B,T,T]: S0 -> FF (scratch) -> M (final)

  float* ws = (float*)d_ws;
  float* q0       = ws;                         // B*T*64 = 262144 f32
  float* k0       = q0 + (size_t)BB * TT * HD;  // 262144
  float* partials = k0 + (size_t)BB * TT * HD;  // B*16*T = 65536
  float* ffsum    = partials + BB * 16 * TT;    // B*T = 4096
  unsigned short* xb  = (unsigned short*)(ffsum + BB * TT);   // B*T*C
  unsigned short* wbT = xb + (size_t)Y_ELEMS;                 // 2304*768
  unsigned short* wpT = wbT + (size_t)N3 * CC;                // 768*768
  unsigned short* Qb  = wpT + (size_t)CC * CC;                // B*NH*T*HD
  unsigned short* Kb  = Qb + (size_t)BB * NH * TT * HD;
  unsigned short* Vt  = Kb + (size_t)BB * NH * TT * HD;
  unsigned short* yhb = Vt + (size_t)BB * NH * TT * HD;       // B*T*C
  // total ws usage ~= 38.5 MB

  // 1. packs: x -> bf16; weights -> transposed bf16
  pack_x<<<Y_ELEMS / (256 * 8), 256, 0, stream>>>(x, xb);
  transpose_pack<<<dim3(CC / 64, N3 / 64), 256, 0, stream>>>(w_attn, wbT, N3);
  transpose_pack<<<dim3(CC / 64, CC / 64), 256, 0, stream>>>(w_proj, wpT, CC);
  // 2. bf16 MFMA QKV GEMM -> packed Qb/Kb/Vt (fuses prep)
  gemm_qkv_bf16<<<dim3(32, 36), 256, 0, stream>>>(xb, wbT, b_attn, Qb, Kb, Vt);
  // 3. fp32 head-0 q,k (precision-critical FF path)
  sgemm_qk0<<<dim3(64, 2), 256, 0, stream>>>(x, w_attn, b_attn, q0, k0);
  // 4. head-0 scores (relu'd, fp32) into Mreg
  score0_kernel<<<dim3(32, 32, BB), 256, 0, stream>>>(q0, k0, Mreg);
  // 5. column-wise exclusive scan (in place): Mreg = FF
  scan_partial<<<dim3(8, 16, BB), 256, 0, stream>>>(Mreg, partials);
  scan_write<<<dim3(8, 16, BB), 256, 0, stream>>>(Mreg, partials);
  // 6. FF_sum
  ffsum_kernel<<<dim3(TT, BB), 256, 0, stream>>>(Mreg, ffsum);
  // 7. MFMA flash attention (reads FF from Mreg) -> bf16 yhb
  attn_mfma<<<dim3(32, NH, BB), 256, 0, stream>>>(Qb, Kb, Vt, Mreg, yhb);
  // 8. M output (overwrites Mreg AFTER attention consumed FF)
  m_kernel<<<4096, 256, 0, stream>>>(ffsum, Mreg);
  // 9. y = yhb @ w_proj + b_proj (bf16 MFMA)
  gemm_proj_bf16<<<dim3(32, 12), 256, 0, stream>>>(yhb, wpT, b_proj, y);
}